// Round 9
// baseline (402.109 us; speedup 1.0000x reference)
//
#include <hip/hip_runtime.h>
#include <cstdint>
#include <cstddef>

typedef __bf16 bf16_t;
typedef __bf16 bf16x4 __attribute__((ext_vector_type(4)));
typedef __bf16 bf16x8 __attribute__((ext_vector_type(8)));
typedef float floatx4 __attribute__((ext_vector_type(4)));

#define NBATCH 2
#define NL     2048
#define NTOK   4096        // NBATCH*NL
#define DMODEL 1024
#define DINNER 2048
#define DSTATE 16
#define DTRANK 64
#define XPN    96          // DT_RANK + 2*D_STATE
#define NCHUNK 64
#define CS     32          // NL / NCHUNK
#define KSPLIT 8           // x_proj split-K slabs

typedef const __attribute__((address_space(1))) void gvoid_t;
typedef __attribute__((address_space(3))) void lds_void_t;

__device__ __forceinline__ void gload_lds16(const bf16_t* g, bf16_t* l) {
  __builtin_amdgcn_global_load_lds((gvoid_t*)g, (lds_void_t*)l, 16, 0, 0);
}

// fast softplus: max(t,0) + log(1+exp(-|t|)); __expf/__logf = single v_exp/v_log.
__device__ __forceinline__ float softplus_fast(float t) {
  return fmaxf(t, 0.f) + __logf(1.f + __expf(-fabsf(t)));
}

// ---------------- elementwise converts (4 separate launches — proven config) ----
__global__ __launch_bounds__(256) void cvt_bf16(const float* __restrict__ src,
                                                bf16_t* __restrict__ dst, int n4) {
  int i = blockIdx.x * 256 + threadIdx.x;
  if (i >= n4) return;
  float4 v = ((const float4*)src)[i];
  bf16x4 o = { (bf16_t)v.x, (bf16_t)v.y, (bf16_t)v.z, (bf16_t)v.w };
  ((bf16x4*)dst)[i] = o;
}

// ---------------- fused add + rmsnorm -> bf16 ----------------
__global__ __launch_bounds__(256) void rmsnorm_kernel(const float* __restrict__ hid,
                                                      const float* __restrict__ res,
                                                      const float* __restrict__ w,
                                                      bf16_t* __restrict__ out) {
  int tok = blockIdx.x, tid = threadIdx.x;
  float4 a = ((const float4*)(hid + (size_t)tok * DMODEL))[tid];
  float4 b = ((const float4*)(res + (size_t)tok * DMODEL))[tid];
  float4 v = { a.x + b.x, a.y + b.y, a.z + b.z, a.w + b.w };
  float ss = v.x*v.x + v.y*v.y + v.z*v.z + v.w*v.w;
  #pragma unroll
  for (int o = 32; o > 0; o >>= 1) ss += __shfl_xor(ss, o);
  __shared__ float sred[4];
  if ((tid & 63) == 0) sred[tid >> 6] = ss;
  __syncthreads();
  float tot = sred[0] + sred[1] + sred[2] + sred[3];
  float scale = rsqrtf(tot * (1.0f / DMODEL) + 1e-5f);
  float4 wv = ((const float4*)w)[tid];
  bf16x4 o = { (bf16_t)(v.x*scale*wv.x), (bf16_t)(v.y*scale*wv.y),
               (bf16_t)(v.z*scale*wv.z), (bf16_t)(v.w*scale*wv.w) };
  ((bf16x4*)out)[(size_t)tok * (DMODEL/4) + tid] = o;
}

// ---- coalesced epilogue: acc[4][4] -> LDS (per-wave 16x64 region) -> 16B stores
template <typename OutT, int MODE>
__device__ __forceinline__ void epilogue_store(const floatx4 (&acc)[4][4],
                                               OutT* __restrict__ C, int ldc,
                                               int row0, int col0,   // wave's 64x64 origin
                                               int wave, int lane, void* smem,
                                               const float* __restrict__ bias) {
  int lm = lane & 15, quad = lane >> 4;
  OutT* ep = (OutT*)smem + wave * 1024;
  constexpr int E = 16 / (int)sizeof(OutT);
  constexpr int CPR = 64 / E;
  constexpr int ITER = 16 * CPR / 64;
  #pragma unroll
  for (int i = 0; i < 4; i++) {
    __syncthreads();
    #pragma unroll
    for (int j = 0; j < 4; j++)
      #pragma unroll
      for (int r = 0; r < 4; r++) {
        float v = acc[i][j][r];
        if (MODE == 1) v = softplus_fast(v + bias[col0 + j*16 + lm]);
        ep[(quad*4 + r) * 64 + j*16 + lm] = (OutT)v;
      }
    __syncthreads();
    #pragma unroll
    for (int k = 0; k < ITER; k++) {
      int ch = k * 64 + lane;
      int rr = ch / CPR, cc = ch % CPR;
      *(float4*)(C + (size_t)(row0 + i*16 + rr) * ldc + col0 + cc*E) =
          *(const float4*)(ep + rr*64 + cc*E);
    }
  }
}

// ---------------- 256x128 GEMM (512 thr, 8 waves), C = A * B^T, BK=64 --------
// LDS swizzle: chunk c of row r at slot c^(r&7) (row&7 == lm&7 on read).
__global__ __launch_bounds__(512) void gemm_bt_256(const bf16_t* __restrict__ A,
                                                   const bf16_t* __restrict__ B,
                                                   bf16_t* __restrict__ C,
                                                   int N, int K, int NBn) {
  __shared__ __align__(16) bf16_t smem[256*64 + 128*64];   // 48 KB
  bf16_t* sA = smem;
  bf16_t* sB = smem + 256 * 64;
  int bx = blockIdx.x;
  int bm = bx / NBn, bn = bx % NBn;
  int tid = threadIdx.x;
  int lane = tid & 63, wave = tid >> 6;
  const bf16_t* Ab = A + (size_t)bm * 256 * K;
  const bf16_t* Bb = B + (size_t)bn * 128 * K;
  floatx4 acc[4][4] = {};
  int wm = (wave & 3) * 64, wn = (wave >> 2) * 64;
  int lm = lane & 15, quad = lane >> 4;

  for (int kk = 0; kk < K; kk += 64) {
    #pragma unroll
    for (int rr = 0; rr < 4; rr++) {   // A: 2048 chunks / 512 thr
      int s = rr * 512 + tid;
      int r = s >> 3, g = ((s & 7) ^ (r & 7)) * 8;
      gload_lds16(Ab + (size_t)r * K + kk + g, sA + (size_t)(rr*512 + wave*64)*8);
    }
    #pragma unroll
    for (int rr = 0; rr < 2; rr++) {   // B: 1024 chunks / 512 thr
      int s = rr * 512 + tid;
      int r = s >> 3, g = ((s & 7) ^ (r & 7)) * 8;
      gload_lds16(Bb + (size_t)r * K + kk + g, sB + (size_t)(rr*512 + wave*64)*8);
    }
    __syncthreads();
    #pragma unroll
    for (int s = 0; s < 2; s++) {
      int kx = ((s*4 + quad) ^ (lm & 7)) * 8;
      bf16x8 a[4], b[4];
      #pragma unroll
      for (int i = 0; i < 4; i++) a[i] = *(const bf16x8*)&sA[(wm + i*16 + lm)*64 + kx];
      #pragma unroll
      for (int j = 0; j < 4; j++) b[j] = *(const bf16x8*)&sB[(wn + j*16 + lm)*64 + kx];
      #pragma unroll
      for (int i = 0; i < 4; i++)
        #pragma unroll
        for (int j = 0; j < 4; j++)
          acc[i][j] = __builtin_amdgcn_mfma_f32_16x16x32_bf16(a[i], b[j], acc[i][j], 0, 0, 0);
    }
    __syncthreads();
  }
  epilogue_store<bf16_t, 0>(acc, C, N, bm*256 + wm, bn*128 + wn, wave, lane, smem, nullptr);
}

// ---------------- 128x128 GEMM (256 thr), C = A * B^T, BK=64 ------------------
template <typename OutT>
__global__ __launch_bounds__(256) void gemm_bt_128(const bf16_t* __restrict__ A,
                                                   const bf16_t* __restrict__ B,
                                                   OutT* __restrict__ C,
                                                   int N, int K, int NBn) {
  __shared__ __align__(16) bf16_t smem[2 * 128 * 64];   // 32 KB
  bf16_t* sA = smem;
  bf16_t* sB = smem + 128 * 64;
  int bx = blockIdx.x;
  int bm = bx / NBn, bn = bx % NBn;
  int tid = threadIdx.x;
  int lane = tid & 63, wave = tid >> 6;
  const bf16_t* Ab = A + (size_t)bm * 128 * K;
  const bf16_t* Bb = B + (size_t)bn * 128 * K;
  int rowS[4], gcol[4];
  #pragma unroll
  for (int rr = 0; rr < 4; rr++) {
    int s = rr * 256 + tid;
    rowS[rr] = s >> 3;
    gcol[rr] = ((s & 7) ^ ((s >> 3) & 7)) * 8;
  }
  floatx4 acc[4][4] = {};
  int wm = (wave & 1) * 64, wn = (wave >> 1) * 64;
  int lm = lane & 15, quad = lane >> 4;

  for (int kk = 0; kk < K; kk += 64) {
    #pragma unroll
    for (int rr = 0; rr < 4; rr++) {
      gload_lds16(Ab + (size_t)rowS[rr] * K + kk + gcol[rr], sA + (size_t)(rr*256 + wave*64)*8);
      gload_lds16(Bb + (size_t)rowS[rr] * K + kk + gcol[rr], sB + (size_t)(rr*256 + wave*64)*8);
    }
    __syncthreads();
    #pragma unroll
    for (int s = 0; s < 2; s++) {
      int kx = ((s*4 + quad) ^ (lm & 7)) * 8;
      bf16x8 a[4], b[4];
      #pragma unroll
      for (int i = 0; i < 4; i++) a[i] = *(const bf16x8*)&sA[(wm + i*16 + lm)*64 + kx];
      #pragma unroll
      for (int j = 0; j < 4; j++) b[j] = *(const bf16x8*)&sB[(wn + j*16 + lm)*64 + kx];
      #pragma unroll
      for (int i = 0; i < 4; i++)
        #pragma unroll
        for (int j = 0; j < 4; j++)
          acc[i][j] = __builtin_amdgcn_mfma_f32_16x16x32_bf16(a[i], b[j], acc[i][j], 0, 0, 0);
    }
    __syncthreads();
  }
  epilogue_store<OutT, 0>(acc, C, N, bm*128 + wm, bn*128 + wn, wave, lane, smem, nullptr);
}

// ---------------- causal depthwise conv(4) + SiLU, 4 channels/thread ----------
__global__ __launch_bounds__(256) void conv_silu(const bf16_t* __restrict__ xz,
                                                 const float* __restrict__ w,
                                                 const float* __restrict__ bias,
                                                 bf16_t* __restrict__ xc) {
  int idx = blockIdx.x * 256 + threadIdx.x;   // over NTOK*DINNER/4
  int e4 = (idx & (DINNER/4 - 1)) * 4;
  int tok = idx >> 9;                         // DINNER/4 = 512
  int l = tok & (NL - 1);
  float4 b4 = *(const float4*)(bias + e4);
  float acc[4] = { b4.x, b4.y, b4.z, b4.w };
  float4 wch[4];                               // wch[i] = taps of channel e4+i
  #pragma unroll
  for (int i = 0; i < 4; i++) wch[i] = ((const float4*)w)[e4 + i];
  #pragma unroll
  for (int k = 0; k < 4; k++) {
    int t = l - 3 + k;
    if (t >= 0) {
      bf16x4 xv = *(const bf16x4*)(xz + (size_t)(tok - 3 + k) * (2*DINNER) + e4);
      acc[0] += (float)xv[0] * ((const float*)&wch[0])[k];
      acc[1] += (float)xv[1] * ((const float*)&wch[1])[k];
      acc[2] += (float)xv[2] * ((const float*)&wch[2])[k];
      acc[3] += (float)xv[3] * ((const float*)&wch[3])[k];
    }
  }
  bf16x4 o;
  #pragma unroll
  for (int i = 0; i < 4; i++) {
    float s = acc[i] / (1.0f + __expf(-acc[i]));
    o[i] = (bf16_t)s;
  }
  *(bf16x4*)(xc + (size_t)tok * DINNER + e4) = o;
}

// ---- x_proj GEMM: (M x 2048) * (96 x 2048)^T, split-K=8, slab outputs -------
__global__ __launch_bounds__(256) void gemm_xproj(const bf16_t* __restrict__ A,
                                                  const bf16_t* __restrict__ B,
                                                  float* __restrict__ slabs) {
  __shared__ __align__(16) bf16_t sA[128 * 64];  // 16 KB
  __shared__ __align__(16) bf16_t sB[96 * 64];   // 12 KB
  int bx = blockIdx.x;                 // 256: bm in [0,32), ks in [0,8)
  int bm = bx >> 3, ks = bx & 7;
  int tid = threadIdx.x, lane = tid & 63, wave = tid >> 6;
  const int K = DINNER;
  const bf16_t* Ab = A + (size_t)bm * 128 * K;
  float* Cs = slabs + (size_t)ks * NTOK * XPN;
  int kbeg = ks * (K / KSPLIT);
  floatx4 acc[2][6] = {};
  int wrow = wave * 32;
  int lm = lane & 15, quad = lane >> 4;
  for (int kk = kbeg; kk < kbeg + K / KSPLIT; kk += 64) {
    #pragma unroll
    for (int rr = 0; rr < 4; rr++) {
      int s = rr * 256 + tid;
      int r = s >> 3, g = ((s & 7) ^ (r & 7)) * 8;
      gload_lds16(Ab + (size_t)r * K + kk + g, sA + (size_t)(rr*256 + wave*64)*8);
    }
    #pragma unroll
    for (int rr = 0; rr < 3; rr++) {
      int s = rr * 256 + tid;
      int r = s >> 3, g = ((s & 7) ^ (r & 7)) * 8;
      gload_lds16(B + (size_t)r * K + kk + g, sB + (size_t)(rr*256 + wave*64)*8);
    }
    __syncthreads();
    #pragma unroll
    for (int s = 0; s < 2; s++) {
      int kx = ((s*4 + quad) ^ (lm & 7)) * 8;
      bf16x8 a[2], b[6];
      #pragma unroll
      for (int i = 0; i < 2; i++) a[i] = *(const bf16x8*)&sA[(wrow + i*16 + lm)*64 + kx];
      #pragma unroll
      for (int j = 0; j < 6; j++) b[j] = *(const bf16x8*)&sB[(j*16 + lm)*64 + kx];
      #pragma unroll
      for (int i = 0; i < 2; i++)
        #pragma unroll
        for (int j = 0; j < 6; j++)
          acc[i][j] = __builtin_amdgcn_mfma_f32_16x16x32_bf16(a[i], b[j], acc[i][j], 0, 0, 0);
    }
    __syncthreads();
  }
  int row0 = bm * 128 + wrow + quad * 4;
  #pragma unroll
  for (int i = 0; i < 2; i++)
    #pragma unroll
    for (int j = 0; j < 6; j++)
      #pragma unroll
      for (int r = 0; r < 4; r++)
        Cs[(size_t)(row0 + i*16 + r) * XPN + j*16 + lm] = acc[i][j][r];
}

// ---- reduce 8 x_proj slabs -> xdbl (fp32) + dtlow (bf16, cols 0..63) --------
__global__ __launch_bounds__(256) void xproj_reduce(const float* __restrict__ slabs,
                                                    float* __restrict__ xdbl,
                                                    bf16_t* __restrict__ dtlow) {
  int i = blockIdx.x * 256 + threadIdx.x;   // NTOK*XPN/4 = 98304 float4 units
  float4 acc = {0.f, 0.f, 0.f, 0.f};
  #pragma unroll
  for (int s = 0; s < KSPLIT; s++) {
    float4 v = *(const float4*)(slabs + (size_t)s * NTOK * XPN + (size_t)i * 4);
    acc.x += v.x; acc.y += v.y; acc.z += v.z; acc.w += v.w;
  }
  *(float4*)(xdbl + (size_t)i * 4) = acc;
  int row = i / (XPN / 4), c = (i % (XPN / 4)) * 4;
  if (c < DTRANK) {
    bf16x4 o = { (bf16_t)acc.x, (bf16_t)acc.y, (bf16_t)acc.z, (bf16_t)acc.w };
    *(bf16x4*)(dtlow + (size_t)row * DTRANK + c) = o;
  }
}

// ---------------- dt_proj GEMM (K=64) + bias + softplus -> bf16 ----------------
__global__ __launch_bounds__(256) void gemm_dtproj(const bf16_t* __restrict__ A,
                                                   const bf16_t* __restrict__ B,
                                                   const float* __restrict__ bias,
                                                   bf16_t* __restrict__ dt) {
  __shared__ __align__(16) bf16_t smem[2 * 128 * 64];   // 32 KB
  bf16_t* sA = smem;
  bf16_t* sB = smem + 128 * 64;
  int bx = blockIdx.x;                 // 512: bm in [0,32), bn in [0,16)
  int bm = bx >> 4, bn = bx & 15;
  int tid = threadIdx.x, lane = tid & 63, wave = tid >> 6;
  #pragma unroll
  for (int rr = 0; rr < 4; rr++) {
    int s = rr * 256 + tid;
    int r = s >> 3, g = (s & 7) ^ (r & 7);
    gload_lds16(A + (size_t)(bm * 128 + r) * 64 + g * 8, sA + (size_t)(rr*256 + wave*64)*8);
    gload_lds16(B + (size_t)(bn * 128 + r) * 64 + g * 8, sB + (size_t)(rr*256 + wave*64)*8);
  }
  __syncthreads();
  int wm = (wave & 1) * 64, wn = (wave >> 1) * 64;
  int lm = lane & 15, q = lane >> 4;
  floatx4 acc[4][4] = {};
  #pragma unroll
  for (int s = 0; s < 2; s++) {
    int kx = ((s * 4 + q) ^ (lm & 7)) * 8;
    bf16x8 a[4], b[4];
    #pragma unroll
    for (int i = 0; i < 4; i++) a[i] = *(const bf16x8*)&sA[(wm + i*16 + lm)*64 + kx];
    #pragma unroll
    for (int j = 0; j < 4; j++) b[j] = *(const bf16x8*)&sB[(wn + j*16 + lm)*64 + kx];
    #pragma unroll
    for (int i = 0; i < 4; i++)
      #pragma unroll
      for (int j = 0; j < 4; j++)
        acc[i][j] = __builtin_amdgcn_mfma_f32_16x16x32_bf16(a[i], b[j], acc[i][j], 0, 0, 0);
  }
  __syncthreads();
  epilogue_store<bf16_t, 1>(acc, dt, DINNER, bm*128 + wm, bn*128 + wn, wave, lane, smem, bias);
}

// ---------------- scan pass A: per-chunk (sum_dt, h_end | h0=0) ----------------
__global__ __launch_bounds__(256) void scan_passA(const bf16_t* __restrict__ dt,
                                                  const bf16_t* __restrict__ x,
                                                  const float* __restrict__ xdbl,
                                                  const float* __restrict__ A_log,
                                                  float* __restrict__ qbuf,
                                                  float* __restrict__ sdbuf) {
  int bx = blockIdx.x;                  // 1024 = b(2) * chunk(64) * dgrp(8)
  int dgrp = bx & 7, chunk = (bx >> 3) & 63, bb = bx >> 9;
  int tid = threadIdx.x;
  int d = dgrp * 256 + tid;
  int t0 = chunk * CS;
  __shared__ float sBC[CS * 32];
  {
    int i = tid * 4;
    int t = i >> 5, c = i & 31;
    float4 v = *(const float4*)(xdbl + (size_t)(bb * NL + t0 + t) * XPN + DTRANK + c);
    *(float4*)(sBC + t * 32 + c) = v;
  }
  float a2[DSTATE];
  {
    const float4* Ar = (const float4*)(A_log + (size_t)d * DSTATE);
    #pragma unroll
    for (int q = 0; q < 4; q++) {
      float4 v = Ar[q];
      a2[q*4+0] = -__expf(v.x) * 1.44269504f;
      a2[q*4+1] = -__expf(v.y) * 1.44269504f;
      a2[q*4+2] = -__expf(v.z) * 1.44269504f;
      a2[q*4+3] = -__expf(v.w) * 1.44269504f;
    }
  }
  __syncthreads();
  float h[DSTATE];
  #pragma unroll
  for (int n = 0; n < DSTATE; n++) h[n] = 0.f;
  float sum_dt = 0.f;
  size_t base = (size_t)(bb * NL + t0) * DINNER + d;
  for (int t = 0; t < CS; t++) {
    float dtv = (float)dt[base + (size_t)t * DINNER];
    float xv  = (float)x [base + (size_t)t * DINNER];
    float dtx = dtv * xv;
    sum_dt += dtv;
    const float* Bt = sBC + t * 32;
    #pragma unroll
    for (int n = 0; n < DSTATE; n++) {
      float da = exp2f(dtv * a2[n]);
      h[n] = da * h[n] + dtx * Bt[n];
    }
  }
  size_t qb = ((size_t)((bb * NCHUNK + chunk) * DINNER + d)) * DSTATE;
  #pragma unroll
  for (int q = 0; q < 4; q++) {
    float4 v = { h[q*4], h[q*4+1], h[q*4+2], h[q*4+3] };
    *(float4*)(qbuf + qb + q*4) = v;
  }
  sdbuf[(size_t)(bb * NCHUNK + chunk) * DINNER + d] = sum_dt;
}

// ---------------- scan pass B: inter-chunk scan; qbuf <- h_start per chunk -----
__global__ __launch_bounds__(256) void scan_passB(const float* __restrict__ A_log,
                                                  const float* __restrict__ sdbuf,
                                                  float* __restrict__ qbuf) {
  int idx = blockIdx.x * 256 + threadIdx.x;   // 65536 = b*DINNER*DSTATE
  int n = idx & 15, dd = (idx >> 4) & (DINNER - 1), bb = idx >> 15;
  float a2 = -__expf(A_log[(size_t)dd * DSTATE + n]) * 1.44269504f;
  float h = 0.f;
  for (int c = 0; c < NCHUNK; c++) {
    size_t q = ((size_t)((bb * NCHUNK + c) * DINNER + dd)) * DSTATE + n;
    float Q = qbuf[q];
    float P = exp2f(a2 * sdbuf[(size_t)(bb * NCHUNK + c) * DINNER + dd]);
    qbuf[q] = h;
    h = P * h + Q;
  }
}

// ---------------- scan pass C: replay from h_start, fused y/gate -> bf16 -------
__global__ __launch_bounds__(256) void scan_passC(const bf16_t* __restrict__ dt,
                                                  const bf16_t* __restrict__ x,
                                                  const bf16_t* __restrict__ xz,
                                                  const float* __restrict__ xdbl,
                                                  const float* __restrict__ A_log,
                                                  const float* __restrict__ Dp,
                                                  const float* __restrict__ qbuf,
                                                  bf16_t* __restrict__ y) {
  int bx = blockIdx.x;
  int dgrp = bx & 7, chunk = (bx >> 3) & 63, bb = bx >> 9;
  int tid = threadIdx.x;
  int d = dgrp * 256 + tid;
  int t0 = chunk * CS;
  __shared__ float sBC[CS * 32];
  {
    int i = tid * 4;
    int t = i >> 5, c = i & 31;
    float4 v = *(const float4*)(xdbl + (size_t)(bb * NL + t0 + t) * XPN + DTRANK + c);
    *(float4*)(sBC + t * 32 + c) = v;
  }
  float a2[DSTATE];
  {
    const float4* Ar = (const float4*)(A_log + (size_t)d * DSTATE);
    #pragma unroll
    for (int q = 0; q < 4; q++) {
      float4 v = Ar[q];
      a2[q*4+0] = -__expf(v.x) * 1.44269504f;
      a2[q*4+1] = -__expf(v.y) * 1.44269504f;
      a2[q*4+2] = -__expf(v.z) * 1.44269504f;
      a2[q*4+3] = -__expf(v.w) * 1.44269504f;
    }
  }
  float h[DSTATE];
  {
    size_t qb = ((size_t)((bb * NCHUNK + chunk) * DINNER + d)) * DSTATE;
    #pragma unroll
    for (int q = 0; q < 4; q++) {
      float4 v = *(const float4*)(qbuf + qb + q*4);
      h[q*4] = v.x; h[q*4+1] = v.y; h[q*4+2] = v.z; h[q*4+3] = v.w;
    }
  }
  float Dv = Dp[d];
  __syncthreads();
  size_t base = (size_t)(bb * NL + t0) * DINNER + d;
  size_t zbase = (size_t)(bb * NL + t0) * (2*DINNER) + DINNER + d;
  for (int t = 0; t < CS; t++) {
    float dtv = (float)dt[base + (size_t)t * DINNER];
    float xv  = (float)x [base + (size_t)t * DINNER];
    float dtx = dtv * xv;
    const float* Bt = sBC + t * 32;
    const float* Ct = Bt + DSTATE;
    float yv = 0.f;
    #pragma unroll
    for (int n = 0; n < DSTATE; n++) {
      float da = exp2f(dtv * a2[n]);
      h[n] = da * h[n] + dtx * Bt[n];
      yv += h[n] * Ct[n];
    }
    yv += Dv * xv;
    float zv = (float)xz[zbase + (size_t)t * (2*DINNER)];
    yv *= zv / (1.0f + __expf(-zv));
    y[base + (size_t)t * DINNER] = (bf16_t)yv;
  }
}

// ---------------- host launcher ----------------
extern "C" void kernel_launch(void* const* d_in, const int* in_sizes, int n_in,
                              void* d_out, int out_size, void* d_ws, size_t ws_size,
                              hipStream_t stream) {
  const float* hidden   = (const float*)d_in[1];
  const float* residual = (const float*)d_in[2];
  const float* norm_w   = (const float*)d_in[3];
  const float* in_proj  = (const float*)d_in[4];
  const float* conv_w   = (const float*)d_in[5];
  const float* conv_b   = (const float*)d_in[6];
  const float* x_proj   = (const float*)d_in[7];
  const float* dt_proj  = (const float*)d_in[8];
  const float* dt_bias  = (const float*)d_in[9];
  const float* A_log    = (const float*)d_in[10];
  const float* D_param  = (const float*)d_in[11];
  const float* out_proj = (const float*)d_in[12];
  float* out = (float*)d_out;

  // Workspace layout (≈119.7 MB, proven). xslabs aliases dead hb/w_in_b.
  char* ws = (char*)d_ws;
  bf16_t* hb      = (bf16_t*)ws;                        // 8 MB   [steps 1-2]
  bf16_t* w_in_b  = (bf16_t*)(ws + ((size_t)8  << 20)); // 8 MB   [steps 0-2]
  float*  xslabs  = (float*)ws;                         // 12.6 MB [steps 4-5]
  size_t off = (size_t)16 << 20;
  auto alloc = [&](size_t n) -> char* {
    char* p = ws + off;
    off = (off + n + 255) & ~(size_t)255;
    return p;
  };
  bf16_t* w_out_b = (bf16_t*)alloc((size_t)DMODEL * DINNER * 2);      // 4 MB
  bf16_t* w_xp_b  = (bf16_t*)alloc((size_t)XPN * DINNER * 2);         // 0.4 MB
  bf16_t* w_dtp_b = (bf16_t*)alloc((size_t)DINNER * DTRANK * 2);      // 0.25 MB
  bf16_t* xzb     = (bf16_t*)alloc((size_t)NTOK * 2*DINNER * 2);      // 32 MB
  bf16_t* xconv   = (bf16_t*)alloc((size_t)NTOK * DINNER * 2);        // 16 MB
  float*  xdbl    = (float*) alloc((size_t)NTOK * XPN * 4);           // 1.5 MB
  bf16_t* dtlow   = (bf16_t*)alloc((size_t)NTOK * DTRANK * 2);        // 0.5 MB
  bf16_t* dtbuf   = (bf16_t*)alloc((size_t)NTOK * DINNER * 2);        // 16 MB
  float*  qbuf    = (float*) alloc((size_t)NBATCH*NCHUNK*DINNER*DSTATE*4); // 16 MB
  float*  sdbuf   = (float*) alloc((size_t)NBATCH*NCHUNK*DINNER*4);   // 1 MB
  bf16_t* ybuf    = (bf16_t*)alloc((size_t)NTOK * DINNER * 2);        // 16 MB
  (void)in_sizes; (void)n_in; (void)out_size; (void)ws_size;

  // 0. weight converts (4 separate launches — r8's fused cvt_all suspected +17us)
  cvt_bf16<<<4096, 256, 0, stream>>>(in_proj,  w_in_b,  (2*DINNER*DMODEL)/4);
  cvt_bf16<<<2048, 256, 0, stream>>>(out_proj, w_out_b, (DMODEL*DINNER)/4);
  cvt_bf16<<<192,  256, 0, stream>>>(x_proj,   w_xp_b,  (XPN*DINNER)/4);
  cvt_bf16<<<128,  256, 0, stream>>>(dt_proj,  w_dtp_b, (DINNER*DTRANK)/4);

  // 1. add + rmsnorm
  rmsnorm_kernel<<<NTOK, 256, 0, stream>>>(hidden, residual, norm_w, hb);
  // 2. xz = h * in_proj^T   (M=4096, N=4096, K=1024) — 256x128 tile
  gemm_bt_256<<<(NTOK/256)*(4*DINNER/128), 512, 0, stream>>>(
      hb, w_in_b, xzb, 2*DINNER, DMODEL, (2*DINNER)/128);
  // 3. causal depthwise conv + silu (4 ch/thread, vectorized)
  conv_silu<<<(NTOK*DINNER/4)/256, 256, 0, stream>>>(xzb, conv_w, conv_b, xconv);
  // 4. x_dbl slabs = x * x_proj^T  (split-K; xslabs aliases dead hb/w_in_b)
  gemm_xproj<<<(NTOK/128)*KSPLIT, 256, 0, stream>>>(xconv, w_xp_b, xslabs);
  // 5. reduce slabs -> xdbl + dtlow
  xproj_reduce<<<(NTOK*XPN/4)/256, 256, 0, stream>>>(xslabs, xdbl, dtlow);
  // 6. dt = softplus(dt_low * dt_proj^T + b)
  gemm_dtproj<<<(NTOK/128)*(DINNER/128), 256, 0, stream>>>(dtlow, w_dtp_b, dt_bias, dtbuf);
  // 7. chunked selective scan
  scan_passA<<<NBATCH*NCHUNK*(DINNER/256), 256, 0, stream>>>(dtbuf, xconv, xdbl, A_log, qbuf, sdbuf);
  scan_passB<<<(NBATCH*DINNER*DSTATE)/256, 256, 0, stream>>>(A_log, sdbuf, qbuf);
  scan_passC<<<NBATCH*NCHUNK*(DINNER/256), 256, 0, stream>>>(dtbuf, xconv, xzb, xdbl, A_log, D_param, qbuf, ybuf);
  // 8. out = y * out_proj^T  (M=4096, N=1024, K=2048)
  gemm_bt_128<float><<<(NTOK/128)*(DMODEL/128), 256, 0, stream>>>(
      ybuf, w_out_b, out, DMODEL, DINNER, DMODEL/128);
}

// Round 10
// 383.049 us; speedup vs baseline: 1.0498x; 1.0498x over previous
//
#include <hip/hip_runtime.h>
#include <cstdint>
#include <cstddef>

typedef __bf16 bf16_t;
typedef __bf16 bf16x4 __attribute__((ext_vector_type(4)));
typedef __bf16 bf16x8 __attribute__((ext_vector_type(8)));
typedef float floatx4 __attribute__((ext_vector_type(4)));

#define NBATCH 2
#define NL     2048
#define NTOK   4096        // NBATCH*NL
#define DMODEL 1024
#define DINNER 2048
#define DSTATE 16
#define DTRANK 64
#define XPN    96          // DT_RANK + 2*D_STATE
#define NCHUNK 64
#define CS     32          // NL / NCHUNK
#define KSPLIT 8           // x_proj split-K slabs

typedef const __attribute__((address_space(1))) void gvoid_t;
typedef __attribute__((address_space(3))) void lds_void_t;

__device__ __forceinline__ void gload_lds16(const bf16_t* g, bf16_t* l) {
  __builtin_amdgcn_global_load_lds((gvoid_t*)g, (lds_void_t*)l, 16, 0, 0);
}

// fast softplus: max(t,0) + log(1+exp(-|t|)); __expf/__logf = single v_exp/v_log.
__device__ __forceinline__ float softplus_fast(float t) {
  return fmaxf(t, 0.f) + __logf(1.f + __expf(-fabsf(t)));
}

// ---------------- prep: rmsnorm (blocks 0..NTOK) + 4 weight cvts (rest) -------
// One dispatch replaces 5. cvt work = CV1+CV2+CV3+CV4 float4 units.
#define CV1 1048576   // in_proj
#define CV2 524288    // out_proj
#define CV3 49152     // x_proj
#define CV4 32768     // dt_proj
#define CVT_BLOCKS ((CV1 + CV2 + CV3 + CV4) / 256)   // 6464
__global__ __launch_bounds__(256) void prep_kernel(
    const float* __restrict__ hid, const float* __restrict__ res,
    const float* __restrict__ nw, bf16_t* __restrict__ hb,
    const float* __restrict__ s1, bf16_t* __restrict__ d1,
    const float* __restrict__ s2, bf16_t* __restrict__ d2,
    const float* __restrict__ s3, bf16_t* __restrict__ d3,
    const float* __restrict__ s4, bf16_t* __restrict__ d4) {
  int tid = threadIdx.x;
  if (blockIdx.x < NTOK) {
    // ---- rmsnorm path ----
    int tok = blockIdx.x;
    float4 a = ((const float4*)(hid + (size_t)tok * DMODEL))[tid];
    float4 b = ((const float4*)(res + (size_t)tok * DMODEL))[tid];
    float4 v = { a.x + b.x, a.y + b.y, a.z + b.z, a.w + b.w };
    float ss = v.x*v.x + v.y*v.y + v.z*v.z + v.w*v.w;
    #pragma unroll
    for (int o = 32; o > 0; o >>= 1) ss += __shfl_xor(ss, o);
    __shared__ float sred[4];
    if ((tid & 63) == 0) sred[tid >> 6] = ss;
    __syncthreads();
    float tot = sred[0] + sred[1] + sred[2] + sred[3];
    float scale = rsqrtf(tot * (1.0f / DMODEL) + 1e-5f);
    float4 wv = ((const float4*)nw)[tid];
    bf16x4 o = { (bf16_t)(v.x*scale*wv.x), (bf16_t)(v.y*scale*wv.y),
                 (bf16_t)(v.z*scale*wv.z), (bf16_t)(v.w*scale*wv.w) };
    ((bf16x4*)hb)[(size_t)tok * (DMODEL/4) + tid] = o;
  } else {
    // ---- convert path ----
    int j = (blockIdx.x - NTOK) * 256 + tid;
    const float* s; bf16_t* d;
    if (j < CV1) { s = s1; d = d1; }
    else if ((j -= CV1) < CV2) { s = s2; d = d2; }
    else if ((j -= CV2) < CV3) { s = s3; d = d3; }
    else { j -= CV3; s = s4; d = d4; }
    float4 v = ((const float4*)s)[j];
    bf16x4 o = { (bf16_t)v.x, (bf16_t)v.y, (bf16_t)v.z, (bf16_t)v.w };
    ((bf16x4*)d)[j] = o;
  }
}

// ---- coalesced epilogue: acc[4][4] -> LDS (per-wave 16x64 region) -> 16B stores
template <typename OutT, int MODE>
__device__ __forceinline__ void epilogue_store(const floatx4 (&acc)[4][4],
                                               OutT* __restrict__ C, int ldc,
                                               int row0, int col0,   // wave's 64x64 origin
                                               int wave, int lane, void* smem,
                                               const float* __restrict__ bias) {
  int lm = lane & 15, quad = lane >> 4;
  OutT* ep = (OutT*)smem + wave * 1024;
  constexpr int E = 16 / (int)sizeof(OutT);
  constexpr int CPR = 64 / E;
  constexpr int ITER = 16 * CPR / 64;
  #pragma unroll
  for (int i = 0; i < 4; i++) {
    __syncthreads();
    #pragma unroll
    for (int j = 0; j < 4; j++)
      #pragma unroll
      for (int r = 0; r < 4; r++) {
        float v = acc[i][j][r];
        if (MODE == 1) v = softplus_fast(v + bias[col0 + j*16 + lm]);
        ep[(quad*4 + r) * 64 + j*16 + lm] = (OutT)v;
      }
    __syncthreads();
    #pragma unroll
    for (int k = 0; k < ITER; k++) {
      int ch = k * 64 + lane;
      int rr = ch / CPR, cc = ch % CPR;
      *(float4*)(C + (size_t)(row0 + i*16 + rr) * ldc + col0 + cc*E) =
          *(const float4*)(ep + rr*64 + cc*E);
    }
  }
}

// ---------------- 256x128 GEMM (512 thr, 8 waves), C = A * B^T, BK=64 --------
__global__ __launch_bounds__(512) void gemm_bt_256(const bf16_t* __restrict__ A,
                                                   const bf16_t* __restrict__ B,
                                                   bf16_t* __restrict__ C,
                                                   int N, int K, int NBn) {
  __shared__ __align__(16) bf16_t smem[256*64 + 128*64];   // 48 KB
  bf16_t* sA = smem;
  bf16_t* sB = smem + 256 * 64;
  int bx = blockIdx.x;
  int bm = bx / NBn, bn = bx % NBn;
  int tid = threadIdx.x;
  int lane = tid & 63, wave = tid >> 6;
  const bf16_t* Ab = A + (size_t)bm * 256 * K;
  const bf16_t* Bb = B + (size_t)bn * 128 * K;
  floatx4 acc[4][4] = {};
  int wm = (wave & 3) * 64, wn = (wave >> 2) * 64;
  int lm = lane & 15, quad = lane >> 4;

  for (int kk = 0; kk < K; kk += 64) {
    #pragma unroll
    for (int rr = 0; rr < 4; rr++) {   // A: 2048 chunks / 512 thr
      int s = rr * 512 + tid;
      int r = s >> 3, g = ((s & 7) ^ (r & 7)) * 8;
      gload_lds16(Ab + (size_t)r * K + kk + g, sA + (size_t)(rr*512 + wave*64)*8);
    }
    #pragma unroll
    for (int rr = 0; rr < 2; rr++) {   // B: 1024 chunks / 512 thr
      int s = rr * 512 + tid;
      int r = s >> 3, g = ((s & 7) ^ (r & 7)) * 8;
      gload_lds16(Bb + (size_t)r * K + kk + g, sB + (size_t)(rr*512 + wave*64)*8);
    }
    __syncthreads();
    #pragma unroll
    for (int s = 0; s < 2; s++) {
      int kx = ((s*4 + quad) ^ (lm & 7)) * 8;
      bf16x8 a[4], b[4];
      #pragma unroll
      for (int i = 0; i < 4; i++) a[i] = *(const bf16x8*)&sA[(wm + i*16 + lm)*64 + kx];
      #pragma unroll
      for (int j = 0; j < 4; j++) b[j] = *(const bf16x8*)&sB[(wn + j*16 + lm)*64 + kx];
      #pragma unroll
      for (int i = 0; i < 4; i++)
        #pragma unroll
        for (int j = 0; j < 4; j++)
          acc[i][j] = __builtin_amdgcn_mfma_f32_16x16x32_bf16(a[i], b[j], acc[i][j], 0, 0, 0);
    }
    __syncthreads();
  }
  epilogue_store<bf16_t, 0>(acc, C, N, bm*256 + wm, bn*128 + wn, wave, lane, smem, nullptr);
}

// ---------------- 128x128 GEMM (256 thr), C = A * B^T, BK=64 ------------------
template <typename OutT>
__global__ __launch_bounds__(256) void gemm_bt_128(const bf16_t* __restrict__ A,
                                                   const bf16_t* __restrict__ B,
                                                   OutT* __restrict__ C,
                                                   int N, int K, int NBn) {
  __shared__ __align__(16) bf16_t smem[2 * 128 * 64];   // 32 KB
  bf16_t* sA = smem;
  bf16_t* sB = smem + 128 * 64;
  int bx = blockIdx.x;
  int bm = bx / NBn, bn = bx % NBn;
  int tid = threadIdx.x;
  int lane = tid & 63, wave = tid >> 6;
  const bf16_t* Ab = A + (size_t)bm * 128 * K;
  const bf16_t* Bb = B + (size_t)bn * 128 * K;
  int rowS[4], gcol[4];
  #pragma unroll
  for (int rr = 0; rr < 4; rr++) {
    int s = rr * 256 + tid;
    rowS[rr] = s >> 3;
    gcol[rr] = ((s & 7) ^ ((s >> 3) & 7)) * 8;
  }
  floatx4 acc[4][4] = {};
  int wm = (wave & 1) * 64, wn = (wave >> 1) * 64;
  int lm = lane & 15, quad = lane >> 4;

  for (int kk = 0; kk < K; kk += 64) {
    #pragma unroll
    for (int rr = 0; rr < 4; rr++) {
      gload_lds16(Ab + (size_t)rowS[rr] * K + kk + gcol[rr], sA + (size_t)(rr*256 + wave*64)*8);
      gload_lds16(Bb + (size_t)rowS[rr] * K + kk + gcol[rr], sB + (size_t)(rr*256 + wave*64)*8);
    }
    __syncthreads();
    #pragma unroll
    for (int s = 0; s < 2; s++) {
      int kx = ((s*4 + quad) ^ (lm & 7)) * 8;
      bf16x8 a[4], b[4];
      #pragma unroll
      for (int i = 0; i < 4; i++) a[i] = *(const bf16x8*)&sA[(wm + i*16 + lm)*64 + kx];
      #pragma unroll
      for (int j = 0; j < 4; j++) b[j] = *(const bf16x8*)&sB[(wn + j*16 + lm)*64 + kx];
      #pragma unroll
      for (int i = 0; i < 4; i++)
        #pragma unroll
        for (int j = 0; j < 4; j++)
          acc[i][j] = __builtin_amdgcn_mfma_f32_16x16x32_bf16(a[i], b[j], acc[i][j], 0, 0, 0);
    }
    __syncthreads();
  }
  epilogue_store<OutT, 0>(acc, C, N, bm*128 + wm, bn*128 + wn, wave, lane, smem, nullptr);
}

// ---------------- causal depthwise conv(4) + SiLU, 4 channels/thread ----------
__global__ __launch_bounds__(256) void conv_silu(const bf16_t* __restrict__ xz,
                                                 const float* __restrict__ w,
                                                 const float* __restrict__ bias,
                                                 bf16_t* __restrict__ xc) {
  int idx = blockIdx.x * 256 + threadIdx.x;   // over NTOK*DINNER/4
  int e4 = (idx & (DINNER/4 - 1)) * 4;
  int tok = idx >> 9;                         // DINNER/4 = 512
  int l = tok & (NL - 1);
  float4 b4 = *(const float4*)(bias + e4);
  float acc[4] = { b4.x, b4.y, b4.z, b4.w };
  float4 wch[4];                               // wch[i] = taps of channel e4+i
  #pragma unroll
  for (int i = 0; i < 4; i++) wch[i] = ((const float4*)w)[e4 + i];
  #pragma unroll
  for (int k = 0; k < 4; k++) {
    int t = l - 3 + k;
    if (t >= 0) {
      bf16x4 xv = *(const bf16x4*)(xz + (size_t)(tok - 3 + k) * (2*DINNER) + e4);
      acc[0] += (float)xv[0] * ((const float*)&wch[0])[k];
      acc[1] += (float)xv[1] * ((const float*)&wch[1])[k];
      acc[2] += (float)xv[2] * ((const float*)&wch[2])[k];
      acc[3] += (float)xv[3] * ((const float*)&wch[3])[k];
    }
  }
  bf16x4 o;
  #pragma unroll
  for (int i = 0; i < 4; i++) {
    float s = acc[i] / (1.0f + __expf(-acc[i]));
    o[i] = (bf16_t)s;
  }
  *(bf16x4*)(xc + (size_t)tok * DINNER + e4) = o;
}

// ---- x_proj GEMM: (M x 2048) * (96 x 2048)^T, split-K=8, slab outputs -------
__global__ __launch_bounds__(256) void gemm_xproj(const bf16_t* __restrict__ A,
                                                  const bf16_t* __restrict__ B,
                                                  float* __restrict__ slabs) {
  __shared__ __align__(16) bf16_t sA[128 * 64];  // 16 KB
  __shared__ __align__(16) bf16_t sB[96 * 64];   // 12 KB
  int bx = blockIdx.x;                 // 256: bm in [0,32), ks in [0,8)
  int bm = bx >> 3, ks = bx & 7;
  int tid = threadIdx.x, lane = tid & 63, wave = tid >> 6;
  const int K = DINNER;
  const bf16_t* Ab = A + (size_t)bm * 128 * K;
  float* Cs = slabs + (size_t)ks * NTOK * XPN;
  int kbeg = ks * (K / KSPLIT);
  floatx4 acc[2][6] = {};
  int wrow = wave * 32;
  int lm = lane & 15, quad = lane >> 4;
  for (int kk = kbeg; kk < kbeg + K / KSPLIT; kk += 64) {
    #pragma unroll
    for (int rr = 0; rr < 4; rr++) {
      int s = rr * 256 + tid;
      int r = s >> 3, g = ((s & 7) ^ (r & 7)) * 8;
      gload_lds16(Ab + (size_t)r * K + kk + g, sA + (size_t)(rr*256 + wave*64)*8);
    }
    #pragma unroll
    for (int rr = 0; rr < 3; rr++) {
      int s = rr * 256 + tid;
      int r = s >> 3, g = ((s & 7) ^ (r & 7)) * 8;
      gload_lds16(B + (size_t)r * K + kk + g, sB + (size_t)(rr*256 + wave*64)*8);
    }
    __syncthreads();
    #pragma unroll
    for (int s = 0; s < 2; s++) {
      int kx = ((s*4 + quad) ^ (lm & 7)) * 8;
      bf16x8 a[2], b[6];
      #pragma unroll
      for (int i = 0; i < 2; i++) a[i] = *(const bf16x8*)&sA[(wrow + i*16 + lm)*64 + kx];
      #pragma unroll
      for (int j = 0; j < 6; j++) b[j] = *(const bf16x8*)&sB[(j*16 + lm)*64 + kx];
      #pragma unroll
      for (int i = 0; i < 2; i++)
        #pragma unroll
        for (int j = 0; j < 6; j++)
          acc[i][j] = __builtin_amdgcn_mfma_f32_16x16x32_bf16(a[i], b[j], acc[i][j], 0, 0, 0);
    }
    __syncthreads();
  }
  int row0 = bm * 128 + wrow + quad * 4;
  #pragma unroll
  for (int i = 0; i < 2; i++)
    #pragma unroll
    for (int j = 0; j < 6; j++)
      #pragma unroll
      for (int r = 0; r < 4; r++)
        Cs[(size_t)(row0 + i*16 + r) * XPN + j*16 + lm] = acc[i][j][r];
}

// ---- reduce 8 x_proj slabs -> xdbl (fp32) + dtlow (bf16, cols 0..63) --------
__global__ __launch_bounds__(256) void xproj_reduce(const float* __restrict__ slabs,
                                                    float* __restrict__ xdbl,
                                                    bf16_t* __restrict__ dtlow) {
  int i = blockIdx.x * 256 + threadIdx.x;   // NTOK*XPN/4 = 98304 float4 units
  float4 acc = {0.f, 0.f, 0.f, 0.f};
  #pragma unroll
  for (int s = 0; s < KSPLIT; s++) {
    float4 v = *(const float4*)(slabs + (size_t)s * NTOK * XPN + (size_t)i * 4);
    acc.x += v.x; acc.y += v.y; acc.z += v.z; acc.w += v.w;
  }
  *(float4*)(xdbl + (size_t)i * 4) = acc;
  int row = i / (XPN / 4), c = (i % (XPN / 4)) * 4;
  if (c < DTRANK) {
    bf16x4 o = { (bf16_t)acc.x, (bf16_t)acc.y, (bf16_t)acc.z, (bf16_t)acc.w };
    *(bf16x4*)(dtlow + (size_t)row * DTRANK + c) = o;
  }
}

// ---------------- dt_proj GEMM (K=64) + bias + softplus -> bf16 ----------------
__global__ __launch_bounds__(256) void gemm_dtproj(const bf16_t* __restrict__ A,
                                                   const bf16_t* __restrict__ B,
                                                   const float* __restrict__ bias,
                                                   bf16_t* __restrict__ dt) {
  __shared__ __align__(16) bf16_t smem[2 * 128 * 64];   // 32 KB
  bf16_t* sA = smem;
  bf16_t* sB = smem + 128 * 64;
  int bx = blockIdx.x;                 // 512: bm in [0,32), bn in [0,16)
  int bm = bx >> 4, bn = bx & 15;
  int tid = threadIdx.x, lane = tid & 63, wave = tid >> 6;
  #pragma unroll
  for (int rr = 0; rr < 4; rr++) {
    int s = rr * 256 + tid;
    int r = s >> 3, g = (s & 7) ^ (r & 7);
    gload_lds16(A + (size_t)(bm * 128 + r) * 64 + g * 8, sA + (size_t)(rr*256 + wave*64)*8);
    gload_lds16(B + (size_t)(bn * 128 + r) * 64 + g * 8, sB + (size_t)(rr*256 + wave*64)*8);
  }
  __syncthreads();
  int wm = (wave & 1) * 64, wn = (wave >> 1) * 64;
  int lm = lane & 15, q = lane >> 4;
  floatx4 acc[4][4] = {};
  #pragma unroll
  for (int s = 0; s < 2; s++) {
    int kx = ((s * 4 + q) ^ (lm & 7)) * 8;
    bf16x8 a[4], b[4];
    #pragma unroll
    for (int i = 0; i < 4; i++) a[i] = *(const bf16x8*)&sA[(wm + i*16 + lm)*64 + kx];
    #pragma unroll
    for (int j = 0; j < 4; j++) b[j] = *(const bf16x8*)&sB[(wn + j*16 + lm)*64 + kx];
    #pragma unroll
    for (int i = 0; i < 4; i++)
      #pragma unroll
      for (int j = 0; j < 4; j++)
        acc[i][j] = __builtin_amdgcn_mfma_f32_16x16x32_bf16(a[i], b[j], acc[i][j], 0, 0, 0);
  }
  __syncthreads();
  epilogue_store<bf16_t, 1>(acc, dt, DINNER, bm*128 + wm, bn*128 + wn, wave, lane, smem, bias);
}

// ---------------- scan pass A: per-chunk (sum_dt, h_end | h0=0) ----------------
__global__ __launch_bounds__(256) void scan_passA(const bf16_t* __restrict__ dt,
                                                  const bf16_t* __restrict__ x,
                                                  const float* __restrict__ xdbl,
                                                  const float* __restrict__ A_log,
                                                  float* __restrict__ qbuf,
                                                  float* __restrict__ sdbuf) {
  int bx = blockIdx.x;                  // 1024 = b(2) * chunk(64) * dgrp(8)
  int dgrp = bx & 7, chunk = (bx >> 3) & 63, bb = bx >> 9;
  int tid = threadIdx.x;
  int d = dgrp * 256 + tid;
  int t0 = chunk * CS;
  __shared__ float sBC[CS * 32];
  {
    int i = tid * 4;
    int t = i >> 5, c = i & 31;
    float4 v = *(const float4*)(xdbl + (size_t)(bb * NL + t0 + t) * XPN + DTRANK + c);
    *(float4*)(sBC + t * 32 + c) = v;
  }
  float a2[DSTATE];
  {
    const float4* Ar = (const float4*)(A_log + (size_t)d * DSTATE);
    #pragma unroll
    for (int q = 0; q < 4; q++) {
      float4 v = Ar[q];
      a2[q*4+0] = -__expf(v.x) * 1.44269504f;
      a2[q*4+1] = -__expf(v.y) * 1.44269504f;
      a2[q*4+2] = -__expf(v.z) * 1.44269504f;
      a2[q*4+3] = -__expf(v.w) * 1.44269504f;
    }
  }
  __syncthreads();
  float h[DSTATE];
  #pragma unroll
  for (int n = 0; n < DSTATE; n++) h[n] = 0.f;
  float sum_dt = 0.f;
  size_t base = (size_t)(bb * NL + t0) * DINNER + d;
  for (int t = 0; t < CS; t++) {
    float dtv = (float)dt[base + (size_t)t * DINNER];
    float xv  = (float)x [base + (size_t)t * DINNER];
    float dtx = dtv * xv;
    sum_dt += dtv;
    const float* Bt = sBC + t * 32;
    #pragma unroll
    for (int n = 0; n < DSTATE; n++) {
      float da = exp2f(dtv * a2[n]);
      h[n] = da * h[n] + dtx * Bt[n];
    }
  }
  size_t qb = ((size_t)((bb * NCHUNK + chunk) * DINNER + d)) * DSTATE;
  #pragma unroll
  for (int q = 0; q < 4; q++) {
    float4 v = { h[q*4], h[q*4+1], h[q*4+2], h[q*4+3] };
    *(float4*)(qbuf + qb + q*4) = v;
  }
  sdbuf[(size_t)(bb * NCHUNK + chunk) * DINNER + d] = sum_dt;
}

// ---------------- scan pass B: inter-chunk scan; qbuf <- h_start per chunk -----
__global__ __launch_bounds__(256) void scan_passB(const float* __restrict__ A_log,
                                                  const float* __restrict__ sdbuf,
                                                  float* __restrict__ qbuf) {
  int idx = blockIdx.x * 256 + threadIdx.x;   // 65536 = b*DINNER*DSTATE
  int n = idx & 15, dd = (idx >> 4) & (DINNER - 1), bb = idx >> 15;
  float a2 = -__expf(A_log[(size_t)dd * DSTATE + n]) * 1.44269504f;
  float h = 0.f;
  for (int c = 0; c < NCHUNK; c++) {
    size_t q = ((size_t)((bb * NCHUNK + c) * DINNER + dd)) * DSTATE + n;
    float Q = qbuf[q];
    float P = exp2f(a2 * sdbuf[(size_t)(bb * NCHUNK + c) * DINNER + dd]);
    qbuf[q] = h;
    h = P * h + Q;
  }
}

// ---------------- scan pass C: replay from h_start, fused y/gate -> bf16 -------
__global__ __launch_bounds__(256) void scan_passC(const bf16_t* __restrict__ dt,
                                                  const bf16_t* __restrict__ x,
                                                  const bf16_t* __restrict__ xz,
                                                  const float* __restrict__ xdbl,
                                                  const float* __restrict__ A_log,
                                                  const float* __restrict__ Dp,
                                                  const float* __restrict__ qbuf,
                                                  bf16_t* __restrict__ y) {
  int bx = blockIdx.x;
  int dgrp = bx & 7, chunk = (bx >> 3) & 63, bb = bx >> 9;
  int tid = threadIdx.x;
  int d = dgrp * 256 + tid;
  int t0 = chunk * CS;
  __shared__ float sBC[CS * 32];
  {
    int i = tid * 4;
    int t = i >> 5, c = i & 31;
    float4 v = *(const float4*)(xdbl + (size_t)(bb * NL + t0 + t) * XPN + DTRANK + c);
    *(float4*)(sBC + t * 32 + c) = v;
  }
  float a2[DSTATE];
  {
    const float4* Ar = (const float4*)(A_log + (size_t)d * DSTATE);
    #pragma unroll
    for (int q = 0; q < 4; q++) {
      float4 v = Ar[q];
      a2[q*4+0] = -__expf(v.x) * 1.44269504f;
      a2[q*4+1] = -__expf(v.y) * 1.44269504f;
      a2[q*4+2] = -__expf(v.z) * 1.44269504f;
      a2[q*4+3] = -__expf(v.w) * 1.44269504f;
    }
  }
  float h[DSTATE];
  {
    size_t qb = ((size_t)((bb * NCHUNK + chunk) * DINNER + d)) * DSTATE;
    #pragma unroll
    for (int q = 0; q < 4; q++) {
      float4 v = *(const float4*)(qbuf + qb + q*4);
      h[q*4] = v.x; h[q*4+1] = v.y; h[q*4+2] = v.z; h[q*4+3] = v.w;
    }
  }
  float Dv = Dp[d];
  __syncthreads();
  size_t base = (size_t)(bb * NL + t0) * DINNER + d;
  size_t zbase = (size_t)(bb * NL + t0) * (2*DINNER) + DINNER + d;
  for (int t = 0; t < CS; t++) {
    float dtv = (float)dt[base + (size_t)t * DINNER];
    float xv  = (float)x [base + (size_t)t * DINNER];
    float dtx = dtv * xv;
    const float* Bt = sBC + t * 32;
    const float* Ct = Bt + DSTATE;
    float yv = 0.f;
    #pragma unroll
    for (int n = 0; n < DSTATE; n++) {
      float da = exp2f(dtv * a2[n]);
      h[n] = da * h[n] + dtx * Bt[n];
      yv += h[n] * Ct[n];
    }
    yv += Dv * xv;
    float zv = (float)xz[zbase + (size_t)t * (2*DINNER)];
    yv *= zv / (1.0f + __expf(-zv));
    y[base + (size_t)t * DINNER] = (bf16_t)yv;
  }
}

// ---------------- host launcher ----------------
extern "C" void kernel_launch(void* const* d_in, const int* in_sizes, int n_in,
                              void* d_out, int out_size, void* d_ws, size_t ws_size,
                              hipStream_t stream) {
  const float* hidden   = (const float*)d_in[1];
  const float* residual = (const float*)d_in[2];
  const float* norm_w   = (const float*)d_in[3];
  const float* in_proj  = (const float*)d_in[4];
  const float* conv_w   = (const float*)d_in[5];
  const float* conv_b   = (const float*)d_in[6];
  const float* x_proj   = (const float*)d_in[7];
  const float* dt_proj  = (const float*)d_in[8];
  const float* dt_bias  = (const float*)d_in[9];
  const float* A_log    = (const float*)d_in[10];
  const float* D_param  = (const float*)d_in[11];
  const float* out_proj = (const float*)d_in[12];
  float* out = (float*)d_out;

  // Workspace layout (≈119.7 MB, proven). xslabs aliases dead hb/w_in_b.
  char* ws = (char*)d_ws;
  bf16_t* hb      = (bf16_t*)ws;                        // 8 MB   [steps 1-2]
  bf16_t* w_in_b  = (bf16_t*)(ws + ((size_t)8  << 20)); // 8 MB   [steps 0-2]
  float*  xslabs  = (float*)ws;                         // 12.6 MB [steps 4-5]
  size_t off = (size_t)16 << 20;
  auto alloc = [&](size_t n) -> char* {
    char* p = ws + off;
    off = (off + n + 255) & ~(size_t)255;
    return p;
  };
  bf16_t* w_out_b = (bf16_t*)alloc((size_t)DMODEL * DINNER * 2);      // 4 MB
  bf16_t* w_xp_b  = (bf16_t*)alloc((size_t)XPN * DINNER * 2);         // 0.4 MB
  bf16_t* w_dtp_b = (bf16_t*)alloc((size_t)DINNER * DTRANK * 2);      // 0.25 MB
  bf16_t* xzb     = (bf16_t*)alloc((size_t)NTOK * 2*DINNER * 2);      // 32 MB
  bf16_t* xconv   = (bf16_t*)alloc((size_t)NTOK * DINNER * 2);        // 16 MB
  float*  xdbl    = (float*) alloc((size_t)NTOK * XPN * 4);           // 1.5 MB
  bf16_t* dtlow   = (bf16_t*)alloc((size_t)NTOK * DTRANK * 2);        // 0.5 MB
  bf16_t* dtbuf   = (bf16_t*)alloc((size_t)NTOK * DINNER * 2);        // 16 MB
  float*  qbuf    = (float*) alloc((size_t)NBATCH*NCHUNK*DINNER*DSTATE*4); // 16 MB
  float*  sdbuf   = (float*) alloc((size_t)NBATCH*NCHUNK*DINNER*4);   // 1 MB
  bf16_t* ybuf    = (bf16_t*)alloc((size_t)NTOK * DINNER * 2);        // 16 MB
  (void)in_sizes; (void)n_in; (void)out_size; (void)ws_size;

  // 0+1. fused: rmsnorm + all weight converts (1 dispatch, was 5)
  prep_kernel<<<NTOK + CVT_BLOCKS, 256, 0, stream>>>(
      hidden, residual, norm_w, hb,
      in_proj, w_in_b, out_proj, w_out_b, x_proj, w_xp_b, dt_proj, w_dtp_b);

  // 2. xz = h * in_proj^T   (M=4096, N=4096, K=1024) — 256x128 tile
  gemm_bt_256<<<(NTOK/256)*(4*DINNER/128), 512, 0, stream>>>(
      hb, w_in_b, xzb, 2*DINNER, DMODEL, (2*DINNER)/128);
  // 3. causal depthwise conv + silu (4 ch/thread, vectorized)
  conv_silu<<<(NTOK*DINNER/4)/256, 256, 0, stream>>>(xzb, conv_w, conv_b, xconv);
  // 4. x_dbl slabs = x * x_proj^T  (split-K; xslabs aliases dead hb/w_in_b)
  gemm_xproj<<<(NTOK/128)*KSPLIT, 256, 0, stream>>>(xconv, w_xp_b, xslabs);
  // 5. reduce slabs -> xdbl + dtlow
  xproj_reduce<<<(NTOK*XPN/4)/256, 256, 0, stream>>>(xslabs, xdbl, dtlow);
  // 6. dt = softplus(dt_low * dt_proj^T + b)
  gemm_dtproj<<<(NTOK/128)*(DINNER/128), 256, 0, stream>>>(dtlow, w_dtp_b, dt_bias, dtbuf);
  // 7. chunked selective scan
  scan_passA<<<NBATCH*NCHUNK*(DINNER/256), 256, 0, stream>>>(dtbuf, xconv, xdbl, A_log, qbuf, sdbuf);
  scan_passB<<<(NBATCH*DINNER*DSTATE)/256, 256, 0, stream>>>(A_log, sdbuf, qbuf);
  scan_passC<<<NBATCH*NCHUNK*(DINNER/256), 256, 0, stream>>>(dtbuf, xconv, xzb, xdbl, A_log, D_param, qbuf, ybuf);
  // 8. out = y * out_proj^T  (M=4096, N=1024, K=2048)
  gemm_bt_128<float><<<(NTOK/128)*(DMODEL/128), 256, 0, stream>>>(
      ybuf, w_out_b, out, DMODEL, DINNER, DMODEL/128);
}